// Round 6
// baseline (1234.825 us; speedup 1.0000x reference)
//
#include <hip/hip_runtime.h>
#include <math.h>

#define Nn 10000
#define En 160000
#define NF 5
#define EF 3
#define Hh 8
#define Cc 128
#define HC 1024
#define Gg 16

#define MROWS 10240   // 80 * 128 (A rows covered by GEMM grid; >= Nn, pad masked)

typedef __attribute__((ext_vector_type(8))) _Float16 half8;
typedef __attribute__((ext_vector_type(4))) float f32x4;

// ---------------- helpers ----------------

__device__ __forceinline__ void gl_lds16(const void* g, void* l) {
    __builtin_amdgcn_global_load_lds((const __attribute__((address_space(1))) void*)g,
                                     (__attribute__((address_space(3))) void*)l, 16, 0, 0);
}

__device__ __forceinline__ float elu_f(float v) {
    return (v > 0.f) ? v : expm1f(v);
}

__device__ __forceinline__ float rl_f(float v, int k) {
    return __int_as_float(__builtin_amdgcn_readlane(__float_as_int(v), k));
}

// ---------------- preprocessing ----------------

// count-only (1 atomic/edge; the 3 ea-sum atomics moved into csr_fill_k)
__global__ void deg_sum_k(const int* __restrict__ dst, int* __restrict__ cnt) {
    int e = blockIdx.x * 256 + threadIdx.x;
    if (e >= En) return;
    atomicAdd(&cnt[dst[e]], 1);
}

// scan (10 elems/thread + one block scan) + group bounds, fused (no division pass —
// aggregate derives 1/deg from rowptr deltas)
__global__ __launch_bounds__(1024) void scan_k(const int* __restrict__ cnt,
                                               int* __restrict__ rowptr,
                                               int* __restrict__ fillptr,
                                               const int* __restrict__ batch,
                                               int* __restrict__ gstart) {
    __shared__ int sh[1024];
    int tid = threadIdx.x;
    int base = tid * 10;
    int loc[10];
    int tsum = 0;
#pragma unroll
    for (int j = 0; j < 10; ++j) {
        int i = base + j;
        int v = (i < Nn) ? cnt[i] : 0;
        loc[j] = tsum;
        tsum += v;
    }
    sh[tid] = tsum;
    __syncthreads();
    for (int off = 1; off < 1024; off <<= 1) {
        int t = (tid >= off) ? sh[tid - off] : 0;
        __syncthreads();
        sh[tid] += t;
        __syncthreads();
    }
    int excl = sh[tid] - tsum;
#pragma unroll
    for (int j = 0; j < 10; ++j) {
        int i = base + j;
        if (i < Nn) {
            rowptr[i] = excl + loc[j];
            fillptr[i] = excl + loc[j];
        }
    }
    if (tid == 1023) rowptr[Nn] = sh[1023];
#pragma unroll
    for (int j = 0; j < 10; ++j) {
        int i = base + j;
        if (i < Nn) {
            int b = batch[i];
            if (i == 0) {
                for (int g = 0; g <= b; ++g) gstart[g] = 0;
            } else {
                int pb = batch[i - 1];
                for (int g = pb + 1; g <= b; ++g) gstart[g] = i;
            }
            if (i == Nn - 1) {
                for (int g = b + 1; g <= Gg; ++g) gstart[g] = Nn;
            }
        }
    }
}

// CSR fill: packed record (ea0,ea1,ea2) + separate srcIdx + loop_attr raw-sum atomics
__global__ void csr_fill_k(const int* __restrict__ src, const int* __restrict__ dst,
                           const float* __restrict__ ea, int* __restrict__ fillptr,
                           float4* __restrict__ eaP, int* __restrict__ srcIdxW,
                           float* __restrict__ loop_attr) {
    int e = blockIdx.x * 256 + threadIdx.x;
    if (e >= En) return;
    int d = dst[e];
    float e0 = ea[e * 3 + 0], e1 = ea[e * 3 + 1], e2 = ea[e * 3 + 2];
    int sv = src[e];
    int pos = atomicAdd(&fillptr[d], 1);
    eaP[pos] = make_float4(e0, e1, e2, __int_as_float(sv));
    srcIdxW[pos] = sv;
    atomicAdd(&loop_attr[d * 3 + 0], e0);
    atomicAdd(&loop_attr[d * 3 + 1], e1);
    atomicAdd(&loop_attr[d * 3 + 2], e2);
}

// ---------------- weight prep (once, all layers) ----------------

__global__ void wae_all_k(const float* __restrict__ We1, const float* __restrict__ ae1,
                          const float* __restrict__ We2, const float* __restrict__ ae2,
                          const float* __restrict__ We3, const float* __restrict__ ae3,
                          const float* __restrict__ We4, const float* __restrict__ ae4,
                          float* __restrict__ w_ae_all) {
    int t = threadIdx.x;
    if (t >= 96) return;
    int l = t / 24, idx = t % 24;
    int f = idx >> 3, h = idx & 7;
    const float* We = (l == 0) ? We1 : (l == 1) ? We2 : (l == 2) ? We3 : We4;
    const float* ae = (l == 0) ? ae1 : (l == 1) ? ae2 : (l == 2) ? ae3 : ae4;
    float s = 0.f;
    for (int c = 0; c < Cc; ++c) s += We[f * HC + h * Cc + c] * ae[h * Cc + c];
    w_ae_all[l * 24 + f * 8 + h] = s;
}

__global__ __launch_bounds__(1024) void wsplit_all_k(const float* __restrict__ W2,
                                                     const float* __restrict__ W3,
                                                     const float* __restrict__ W4,
                                                     _Float16* __restrict__ Wt16) {
    __shared__ float tile[32][33];
    int z = blockIdx.z;
    const float* W = (z == 0) ? W2 : (z == 1) ? W3 : W4;
    int nb = blockIdx.x * 32, kb = blockIdx.y * 32;
    tile[threadIdx.y][threadIdx.x] = W[(size_t)(kb + threadIdx.y) * HC + nb + threadIdx.x];
    __syncthreads();
    float x = tile[threadIdx.x][threadIdx.y];   // W[kb+tx][nb+ty]
    int n = nb + threadIdx.y, k = kb + threadIdx.x;
    Wt16[(size_t)z * HC * HC + (size_t)n * HC + k] = (_Float16)x;
}

// ---------------- GEMMs (fused with a_src/a_dst head dots) ----------------

// layer-1 K=5 GEMM + per-head attention dots
__global__ void gemm_k5(const float* __restrict__ x, const float* __restrict__ Wm,
                        const float* __restrict__ a_s, const float* __restrict__ a_d,
                        _Float16* __restrict__ out16,
                        float* __restrict__ a_srcB, float* __restrict__ a_dstB) {
    int n = blockIdx.x;
    int tid = threadIdx.x;
    __shared__ float xr[8];
    __shared__ float vrow[HC];
    if (tid < NF) xr[tid] = x[n * NF + tid];
    __syncthreads();
    float x0 = xr[0], x1 = xr[1], x2 = xr[2], x3 = xr[3], x4 = xr[4];
    for (int j = tid; j < HC; j += 256) {
        float v = x0 * Wm[j] + x1 * Wm[HC + j] + x2 * Wm[2 * HC + j]
                + x3 * Wm[3 * HC + j] + x4 * Wm[4 * HC + j];
        out16[(size_t)n * HC + j] = (_Float16)v;
        vrow[j] = v;
    }
    __syncthreads();
    int w = tid >> 6, lane = tid & 63;
#pragma unroll
    for (int q = 0; q < 2; ++q) {
        int h = w * 2 + q;
        float v0 = vrow[h * Cc + lane], v1 = vrow[h * Cc + 64 + lane];
        float s1 = v0 * a_s[h * Cc + lane] + v1 * a_s[h * Cc + 64 + lane];
        float s2 = v0 * a_d[h * Cc + lane] + v1 * a_d[h * Cc + 64 + lane];
#pragma unroll
        for (int off = 32; off; off >>= 1) {
            s1 += __shfl_xor(s1, off);
            s2 += __shfl_xor(s2, off);
        }
        if (lane == 0) { a_srcB[n * 8 + h] = s1; a_dstB[n * 8 + h] = s2; }
    }
}

// fp16 MFMA GEMM, XCD-aware decode + DOUBLE-BUFFERED 2-phase K-loop (T3-min recipe):
// STAGE(next) issued before compute(current); single vmcnt-drain+barrier per K-step
// (was: stage -> drain+barrier -> compute -> barrier). HBM latency of the staging
// loads hides under the 16 MFMAs; one barrier/iter instead of two.
__global__ __launch_bounds__(256) void gemm_mfma(const _Float16* __restrict__ A,
                                                 const _Float16* __restrict__ Bt,
                                                 const float* __restrict__ a_s,
                                                 const float* __restrict__ a_d,
                                                 _Float16* __restrict__ C16,
                                                 float* __restrict__ a_srcB,
                                                 float* __restrict__ a_dstB) {
    __shared__ _Float16 As[2][128 * 32];
    __shared__ _Float16 Bs[2][128 * 32];
    __shared__ float ps[128][2];
    __shared__ float pd[128][2];
    int tid = threadIdx.x;
    int wave = tid >> 6, lane = tid & 63;
    int wr = wave >> 1, wc = wave & 1;
    int L = blockIdx.y * 8 + blockIdx.x;
    int rblk = (L & 7) + 8 * (L >> 6);
    int cblk = (L >> 3) & 7;
    int row0 = rblk * 128;
    int col0 = cblk * 128;
    int h = cblk;   // head

    f32x4 acc[4][4];
#pragma unroll
    for (int i = 0; i < 4; ++i)
#pragma unroll
        for (int j = 0; j < 4; ++j) acc[i][j] = (f32x4){0.f, 0.f, 0.f, 0.f};

    int srow = lane >> 2;          // quad covers 64 contiguous bytes of one row
    int scol = (lane & 3) * 8;
    int fr = lane & 15;
    int fk = (lane >> 4) * 8;

    const _Float16* Ab = A + (size_t)row0 * 1024 + scol;
    const _Float16* Bb = Bt + (size_t)col0 * 1024 + scol;

    // prologue: stage tile 0 into buf 0
#pragma unroll
    for (int cc = 0; cc < 2; ++cc) {
        int c = wave + cc * 4;
        int r = c * 16 + srow;
        gl_lds16(Ab + (size_t)r * 1024, &As[0][c * 512 + lane * 8]);
        gl_lds16(Bb + (size_t)r * 1024, &Bs[0][c * 512 + lane * 8]);
    }
    __syncthreads();   // drains vmcnt (compiler-inserted) — tile 0 resident

    for (int t = 0; t < 32; ++t) {
        int cur = t & 1;
        // issue next-tile stage (lands during MFMA; drained at the barrier below)
        if (t + 1 < 32) {
            int kb = (t + 1) * 32;
#pragma unroll
            for (int cc = 0; cc < 2; ++cc) {
                int c = wave + cc * 4;
                int r = c * 16 + srow;
                gl_lds16(Ab + (size_t)r * 1024 + kb, &As[cur ^ 1][c * 512 + lane * 8]);
                gl_lds16(Bb + (size_t)r * 1024 + kb, &Bs[cur ^ 1][c * 512 + lane * 8]);
            }
        }
        half8 af[4], bf[4];
#pragma unroll
        for (int i = 0; i < 4; ++i)
            af[i] = *(const half8*)&As[cur][(wr * 64 + i * 16 + fr) * 32 + fk];
#pragma unroll
        for (int j = 0; j < 4; ++j)
            bf[j] = *(const half8*)&Bs[cur][(wc * 64 + j * 16 + fr) * 32 + fk];
#pragma unroll
        for (int i = 0; i < 4; ++i)
#pragma unroll
            for (int j = 0; j < 4; ++j)
                acc[i][j] = __builtin_amdgcn_mfma_f32_16x16x32_f16(af[i], bf[j], acc[i][j],
                                                                   0, 0, 0);
        __syncthreads();   // drain vmcnt (next tile landed) + release cur buf
    }

    int cn = lane & 15, rq = (lane >> 4) * 4;
    // C write
#pragma unroll
    for (int i = 0; i < 4; ++i) {
        int rbase = row0 + wr * 64 + i * 16 + rq;
#pragma unroll
        for (int j = 0; j < 4; ++j) {
            int col = col0 + wc * 64 + j * 16 + cn;
#pragma unroll
            for (int r = 0; r < 4; ++r) {
                int row = rbase + r;
                if (row < Nn) C16[(size_t)row * HC + col] = (_Float16)acc[i][j][r];
            }
        }
    }
    // fused a_src/a_dst dots over this head's 128 channels
    float asv[4], adv[4];
#pragma unroll
    for (int j = 0; j < 4; ++j) {
        int c = wc * 64 + j * 16 + cn;
        asv[j] = a_s[h * Cc + c];
        adv[j] = a_d[h * Cc + c];
    }
#pragma unroll
    for (int i = 0; i < 4; ++i)
#pragma unroll
        for (int r = 0; r < 4; ++r) {
            float rs = acc[i][0][r] * asv[0] + acc[i][1][r] * asv[1]
                     + acc[i][2][r] * asv[2] + acc[i][3][r] * asv[3];
            float rd = acc[i][0][r] * adv[0] + acc[i][1][r] * adv[1]
                     + acc[i][2][r] * adv[2] + acc[i][3][r] * adv[3];
#pragma unroll
            for (int off = 1; off < 16; off <<= 1) {
                rs += __shfl_xor(rs, off);
                rd += __shfl_xor(rd, off);
            }
            if (cn == 0) {
                int rib = wr * 64 + i * 16 + rq + r;
                ps[rib][wc] = rs;
                pd[rib][wc] = rd;
            }
        }
    __syncthreads();
    if (tid < 128) {
        int row = row0 + tid;
        if (row < Nn) {
            a_srcB[row * 8 + h] = ps[tid][0] + ps[tid][1];
            a_dstB[row * 8 + h] = pd[tid][0] + pd[tid][1];
        }
    }
}

// ---------------- fused attention aggregate ----------------

// 2 WAVES PER NODE, 2 nodes per 256-block (grid = Nn/2, Nn even).
// Round-2 structure (known-good: 57.4 us, VGPR 56, no spills), launch bound raised
// (256,4)->(256,8): VGPR cap 64 >= current 56, doubles residency ceiling for
// latency hiding (occupancy was 32% with no resource limiter — bound-capped).
// Coalesced metadata (srcIdx+eaP per 64 edges) + readlane distribution, 4-edge
// unroll (8-edge spilled: r3). Cross-wave combine via conflict-free LDS, 1 barrier.
// mode 0: out = elu(agg+bias) -> fp16 into A2; mode 1: head-mean+bias+elu dot lin_w.
__global__ __launch_bounds__(256, 8) void aggregate_k(const _Float16* __restrict__ xl16,
                                                      const float4* __restrict__ eaP,
                                                      const int* __restrict__ srcIdx,
                                                      const float* __restrict__ loop_attr,
                                                      const float* __restrict__ a_srcB,
                                                      const float* __restrict__ a_dstB,
                                                      const float* __restrict__ w_ae,
                                                      const int* __restrict__ rowptr,
                                                      const float* __restrict__ bias,
                                                      const float* __restrict__ lin_w,
                                                      _Float16* __restrict__ A2,
                                                      float* __restrict__ dnode,
                                                      int raw_mode) {
    __shared__ float cmbA[2][4][256];   // [node][j4][lane*4] — lane-contiguous float4
    __shared__ float cmbS[2][64];
    int tid = threadIdx.x;
    int lane = tid & 63;
    int wav = tid >> 6;
    int local = wav >> 1;                // node within block (0/1)
    int sub = __builtin_amdgcn_readfirstlane(wav & 1);  // edge-half (uniform)
    int n = __builtin_amdgcn_readfirstlane(blockIdx.x * 2 + local);
    int beg = __builtin_amdgcn_readfirstlane(rowptr[n]);
    int end = __builtin_amdgcn_readfirstlane(rowptr[n + 1]);
    int deg = end - beg;
    int hc = lane >> 3;                  // this lane's head

    float w0c = w_ae[hc], w1c = w_ae[8 + hc], w2c = w_ae[16 + hc];
    float adst_n = a_dstB[n * 8 + hc];
    float asrc_n = a_srcB[n * 8 + hc];
    float invd = 1.0f / fmaxf((float)deg, 1.0f);
    float f0 = loop_attr[n * 3 + 0] * invd;
    float f1 = loop_attr[n * 3 + 1] * invd;
    float f2 = loop_attr[n * 3 + 2] * invd;
    float av = asrc_n + adst_n + f0 * w0c + f1 * w1c + f2 * w2c;
    float aself = (av > 0.f) ? av : 0.2f * av;   // softmax shift; self weight = 1

    int hw = (deg + 1) >> 1;
    int myBeg = beg + sub * hw;
    int myEnd = sub ? end : beg + hw;

    int loff = lane * 16;
    float acc[16];
    float s;
    if (sub == 0) {
        // self term (weight exp(0) = 1)
        const _Float16* rp = xl16 + (size_t)n * HC + loff;
        half8 r0 = *(const half8*)rp;
        half8 r1 = *(const half8*)(rp + 8);
#pragma unroll
        for (int j = 0; j < 8; ++j) {
            acc[j] = (float)r0[j];
            acc[8 + j] = (float)r1[j];
        }
        s = 1.0f;
    } else {
#pragma unroll
        for (int j = 0; j < 16; ++j) acc[j] = 0.f;
        s = 0.0f;
    }

    for (int base = myBeg; base < myEnd; base += 64) {
        int cnt = myEnd - base;
        if (cnt > 64) cnt = 64;
        int li = base + ((lane < cnt) ? lane : 0);
        int src_l = srcIdx[li];          // coalesced
        float4 e_l = eaP[li];            // coalesced
        for (int k = 0; k < cnt; k += 4) {
            int k1 = (k + 1 < cnt) ? k + 1 : k;
            int k2 = (k + 2 < cnt) ? k + 2 : k;
            int k3 = (k + 3 < cnt) ? k + 3 : k;
            bool v1 = (k + 1 < cnt), v2 = (k + 2 < cnt), v3 = (k + 3 < cnt);
            int s0 = __builtin_amdgcn_readlane(src_l, k);
            int s1 = __builtin_amdgcn_readlane(src_l, k1);
            int s2 = __builtin_amdgcn_readlane(src_l, k2);
            int s3 = __builtin_amdgcn_readlane(src_l, k3);
            float e0x = rl_f(e_l.x, k),  e0y = rl_f(e_l.y, k),  e0z = rl_f(e_l.z, k);
            float e1x = rl_f(e_l.x, k1), e1y = rl_f(e_l.y, k1), e1z = rl_f(e_l.z, k1);
            float e2x = rl_f(e_l.x, k2), e2y = rl_f(e_l.y, k2), e2z = rl_f(e_l.z, k2);
            float e3x = rl_f(e_l.x, k3), e3y = rl_f(e_l.y, k3), e3z = rl_f(e_l.z, k3);
            float as0 = a_srcB[s0 * 8 + hc], as1 = a_srcB[s1 * 8 + hc];
            float as2 = a_srcB[s2 * 8 + hc], as3 = a_srcB[s3 * 8 + hc];
            const _Float16* p0 = xl16 + (size_t)s0 * HC + loff;
            const _Float16* p1 = xl16 + (size_t)s1 * HC + loff;
            const _Float16* p2 = xl16 + (size_t)s2 * HC + loff;
            const _Float16* p3 = xl16 + (size_t)s3 * HC + loff;
            half8 q0a = *(const half8*)p0, q0b = *(const half8*)(p0 + 8);
            half8 q1a = *(const half8*)p1, q1b = *(const half8*)(p1 + 8);
            half8 q2a = *(const half8*)p2, q2b = *(const half8*)(p2 + 8);
            half8 q3a = *(const half8*)p3, q3b = *(const half8*)(p3 + 8);
            float al0 = as0 + adst_n + e0x * w0c + e0y * w1c + e0z * w2c;
            float al1 = as1 + adst_n + e1x * w0c + e1y * w1c + e1z * w2c;
            float al2 = as2 + adst_n + e2x * w0c + e2y * w1c + e2z * w2c;
            float al3 = as3 + adst_n + e3x * w0c + e3y * w1c + e3z * w2c;
            al0 = (al0 > 0.f) ? al0 : 0.2f * al0;
            al1 = (al1 > 0.f) ? al1 : 0.2f * al1;
            al2 = (al2 > 0.f) ? al2 : 0.2f * al2;
            al3 = (al3 > 0.f) ? al3 : 0.2f * al3;
            float u0 = __expf(al0 - aself);
            float u1 = v1 ? __expf(al1 - aself) : 0.f;
            float u2 = v2 ? __expf(al2 - aself) : 0.f;
            float u3 = v3 ? __expf(al3 - aself) : 0.f;
            s += u0 + u1 + u2 + u3;
#pragma unroll
            for (int j = 0; j < 8; ++j) {
                float t0 = acc[j], t1 = acc[8 + j];
                t0 = fmaf(u0, (float)q0a[j], t0);  t1 = fmaf(u0, (float)q0b[j], t1);
                t0 = fmaf(u1, (float)q1a[j], t0);  t1 = fmaf(u1, (float)q1b[j], t1);
                t0 = fmaf(u2, (float)q2a[j], t0);  t1 = fmaf(u2, (float)q2b[j], t1);
                t0 = fmaf(u3, (float)q3a[j], t0);  t1 = fmaf(u3, (float)q3b[j], t1);
                acc[j] = t0; acc[8 + j] = t1;
            }
        }
    }

    // cross-wave combine (conflict-free: per-lane-contiguous float4, stride 16B)
    if (sub == 1) {
#pragma unroll
        for (int j4 = 0; j4 < 4; ++j4)
            *(float4*)&cmbA[local][j4][lane * 4] =
                make_float4(acc[j4 * 4 + 0], acc[j4 * 4 + 1],
                            acc[j4 * 4 + 2], acc[j4 * 4 + 3]);
        cmbS[local][lane] = s;
    }
    __syncthreads();
    if (sub == 1) return;

    s += cmbS[local][lane];
#pragma unroll
    for (int j4 = 0; j4 < 4; ++j4) {
        float4 c4 = *(const float4*)&cmbA[local][j4][lane * 4];
        acc[j4 * 4 + 0] += c4.x;
        acc[j4 * 4 + 1] += c4.y;
        acc[j4 * 4 + 2] += c4.z;
        acc[j4 * 4 + 3] += c4.w;
    }
    float inv = 1.f / (s + 1e-16f);

    if (!raw_mode) {
        int ch = loff;
        half8 hv0, hv1;
#pragma unroll
        for (int j = 0; j < 8; ++j) {
            hv0[j] = (_Float16)elu_f(fmaf(acc[j], inv, bias[ch + j]));
            hv1[j] = (_Float16)elu_f(fmaf(acc[8 + j], inv, bias[ch + 8 + j]));
        }
        _Float16* p = A2 + (size_t)n * 1024 + ch;
        *(half8*)p = hv0;
        *(half8*)(p + 8) = hv1;
    } else {
        // normalize, then head-mean over the 8 lanes sharing lane&7
#pragma unroll
        for (int j = 0; j < 16; ++j) acc[j] *= inv;
#pragma unroll
        for (int off = 8; off < 64; off <<= 1)
#pragma unroll
            for (int j = 0; j < 16; ++j) acc[j] += __shfl_xor(acc[j], off);
        int c0 = (lane & 7) * 16;
        float partial = 0.f;
#pragma unroll
        for (int j = 0; j < 16; ++j) {
            float v = elu_f(acc[j] * 0.125f + bias[c0 + j]);
            partial = fmaf(v, lin_w[c0 + j], partial);
        }
#pragma unroll
        for (int off = 1; off < 8; off <<= 1) partial += __shfl_xor(partial, off);
        if (lane == 0) dnode[n] = partial;
    }
}

// ---------------- pooling: reduce per-node scalars per group ----------------

__global__ __launch_bounds__(256) void pool_final_k(const float* __restrict__ dnode,
                                                    const int* __restrict__ gstart,
                                                    const float* __restrict__ lin_b,
                                                    float* __restrict__ out) {
    __shared__ float sh[256];
    int g = blockIdx.x;
    int tid = threadIdx.x;
    int s = gstart[g], e = gstart[g + 1];
    float acc = 0.f;
    for (int n = s + tid; n < e; n += 256) acc += dnode[n];
    sh[tid] = acc;
    __syncthreads();
    for (int off = 128; off; off >>= 1) {
        if (tid < off) sh[tid] += sh[tid + off];
        __syncthreads();
    }
    if (tid == 0) out[g] = sh[0] / fmaxf((float)(e - s), 1.f) + lin_b[0];
}

// ---------------- launch ----------------

extern "C" void kernel_launch(void* const* d_in, const int* in_sizes, int n_in,
                              void* d_out, int out_size, void* d_ws, size_t ws_size,
                              hipStream_t stream) {
    const float* x = (const float*)d_in[0];
    const int* ei = (const int*)d_in[1];
    const float* ea = (const float*)d_in[2];
    const int* batch = (const int*)d_in[3];
    const float *Wl[4], *Wel[4], *asl[4], *adl[4], *ael[4], *bl[4];
    for (int l = 0; l < 4; ++l) {
        Wl[l] = (const float*)d_in[4 + 6 * l];
        Wel[l] = (const float*)d_in[5 + 6 * l];
        asl[l] = (const float*)d_in[6 + 6 * l];
        adl[l] = (const float*)d_in[7 + 6 * l];
        ael[l] = (const float*)d_in[8 + 6 * l];
        bl[l] = (const float*)d_in[9 + 6 * l];
    }
    const float* lin_w = (const float*)d_in[28];
    const float* lin_b = (const float*)d_in[29];
    const int* srcA = ei;
    const int* dstA = ei + En;

    float* Wp = (float*)d_ws;
    size_t o = 0;
    _Float16* A2 = (_Float16*)(Wp + o); o += (size_t)MROWS * 512;        // elu acts fp16
    _Float16* Wt16 = (_Float16*)(Wp + o); o += (size_t)3 * HC * HC / 2;  // 3 fp16 W^T
    _Float16* xl16 = (_Float16*)(Wp + o); o += (size_t)Nn * HC / 2;      // xl fp16
    float4* eaP = (float4*)(Wp + o); o += (size_t)En * 4;                // packed ea
    int* srcIdx = (int*)(Wp + o); o += En;                               // CSR src list
    float* loop_attr = Wp + o; o += Nn * 3;                              // RAW ea sums
    int* cnt = (int*)(Wp + o); o += Nn;
    int* rowptr = (int*)(Wp + o); o += Nn + 1;
    int* fillptr = (int*)(Wp + o); o += Nn;
    int* gstart = (int*)(Wp + o); o += Gg + 1;
    float* a_srcB = Wp + o; o += Nn * Hh;
    float* a_dstB = Wp + o; o += Nn * Hh;
    float* w_ae_all = Wp + o; o += 128;
    float* dnode = Wp + o; o += Nn;

    hipMemsetAsync(cnt, 0, Nn * sizeof(int), stream);
    hipMemsetAsync(loop_attr, 0, Nn * 3 * sizeof(float), stream);

    deg_sum_k<<<(En + 255) / 256, 256, 0, stream>>>(dstA, cnt);
    scan_k<<<1, 1024, 0, stream>>>(cnt, rowptr, fillptr, batch, gstart);
    csr_fill_k<<<(En + 255) / 256, 256, 0, stream>>>(srcA, dstA, ea, fillptr, eaP,
                                                     srcIdx, loop_attr);
    wae_all_k<<<1, 128, 0, stream>>>(Wel[0], ael[0], Wel[1], ael[1], Wel[2], ael[2],
                                     Wel[3], ael[3], w_ae_all);
    wsplit_all_k<<<dim3(32, 32, 3), dim3(32, 32), 0, stream>>>(Wl[1], Wl[2], Wl[3], Wt16);

    for (int l = 0; l < 4; ++l) {
        if (l == 0)
            gemm_k5<<<Nn, 256, 0, stream>>>(x, Wl[0], asl[0], adl[0], xl16, a_srcB, a_dstB);
        else
            gemm_mfma<<<dim3(8, MROWS / 128 / 8 * 8), 256, 0, stream>>>(
                A2, Wt16 + (size_t)(l - 1) * HC * HC, asl[l], adl[l], xl16, a_srcB, a_dstB);
        aggregate_k<<<Nn / 2, 256, 0, stream>>>(xl16, eaP, srcIdx, loop_attr, a_srcB,
                                                a_dstB, w_ae_all + l * 24, rowptr,
                                                bl[l], lin_w, A2, dnode,
                                                (l == 3) ? 1 : 0);
    }
    pool_final_k<<<Gg, 256, 0, stream>>>(dnode, gstart, lin_b, (float*)d_out);
}

// Round 7
// 551.503 us; speedup vs baseline: 2.2390x; 2.2390x over previous
//
#include <hip/hip_runtime.h>
#include <math.h>

#define Nn 10000
#define En 160000
#define NF 5
#define EF 3
#define Hh 8
#define Cc 128
#define HC 1024
#define Gg 16

#define MROWS 10240   // 80 * 128 (A rows covered by GEMM grid; >= Nn, pad masked)

typedef __attribute__((ext_vector_type(8))) _Float16 half8;
typedef __attribute__((ext_vector_type(4))) float f32x4;

// ---------------- helpers ----------------

__device__ __forceinline__ void gl_lds16(const void* g, void* l) {
    __builtin_amdgcn_global_load_lds((const __attribute__((address_space(1))) void*)g,
                                     (__attribute__((address_space(3))) void*)l, 16, 0, 0);
}

__device__ __forceinline__ float elu_f(float v) {
    return (v > 0.f) ? v : expm1f(v);
}

__device__ __forceinline__ float rl_f(float v, int k) {
    return __int_as_float(__builtin_amdgcn_readlane(__float_as_int(v), k));
}

// ---------------- preprocessing ----------------

// count-only (1 atomic/edge; the 3 ea-sum atomics moved into csr_fill_k)
__global__ void deg_sum_k(const int* __restrict__ dst, int* __restrict__ cnt) {
    int e = blockIdx.x * 256 + threadIdx.x;
    if (e >= En) return;
    atomicAdd(&cnt[dst[e]], 1);
}

// scan (10 elems/thread + one block scan) + group bounds, fused (no division pass —
// aggregate derives 1/deg from rowptr deltas)
__global__ __launch_bounds__(1024) void scan_k(const int* __restrict__ cnt,
                                               int* __restrict__ rowptr,
                                               int* __restrict__ fillptr,
                                               const int* __restrict__ batch,
                                               int* __restrict__ gstart) {
    __shared__ int sh[1024];
    int tid = threadIdx.x;
    int base = tid * 10;
    int loc[10];
    int tsum = 0;
#pragma unroll
    for (int j = 0; j < 10; ++j) {
        int i = base + j;
        int v = (i < Nn) ? cnt[i] : 0;
        loc[j] = tsum;
        tsum += v;
    }
    sh[tid] = tsum;
    __syncthreads();
    for (int off = 1; off < 1024; off <<= 1) {
        int t = (tid >= off) ? sh[tid - off] : 0;
        __syncthreads();
        sh[tid] += t;
        __syncthreads();
    }
    int excl = sh[tid] - tsum;
#pragma unroll
    for (int j = 0; j < 10; ++j) {
        int i = base + j;
        if (i < Nn) {
            rowptr[i] = excl + loc[j];
            fillptr[i] = excl + loc[j];
        }
    }
    if (tid == 1023) rowptr[Nn] = sh[1023];
#pragma unroll
    for (int j = 0; j < 10; ++j) {
        int i = base + j;
        if (i < Nn) {
            int b = batch[i];
            if (i == 0) {
                for (int g = 0; g <= b; ++g) gstart[g] = 0;
            } else {
                int pb = batch[i - 1];
                for (int g = pb + 1; g <= b; ++g) gstart[g] = i;
            }
            if (i == Nn - 1) {
                for (int g = b + 1; g <= Gg; ++g) gstart[g] = Nn;
            }
        }
    }
}

// CSR fill: packed record (ea0,ea1,ea2) + separate srcIdx + loop_attr raw-sum atomics
__global__ void csr_fill_k(const int* __restrict__ src, const int* __restrict__ dst,
                           const float* __restrict__ ea, int* __restrict__ fillptr,
                           float4* __restrict__ eaP, int* __restrict__ srcIdxW,
                           float* __restrict__ loop_attr) {
    int e = blockIdx.x * 256 + threadIdx.x;
    if (e >= En) return;
    int d = dst[e];
    float e0 = ea[e * 3 + 0], e1 = ea[e * 3 + 1], e2 = ea[e * 3 + 2];
    int sv = src[e];
    int pos = atomicAdd(&fillptr[d], 1);
    eaP[pos] = make_float4(e0, e1, e2, __int_as_float(sv));
    srcIdxW[pos] = sv;
    atomicAdd(&loop_attr[d * 3 + 0], e0);
    atomicAdd(&loop_attr[d * 3 + 1], e1);
    atomicAdd(&loop_attr[d * 3 + 2], e2);
}

// ---------------- weight prep (once, all layers) ----------------

__global__ void wae_all_k(const float* __restrict__ We1, const float* __restrict__ ae1,
                          const float* __restrict__ We2, const float* __restrict__ ae2,
                          const float* __restrict__ We3, const float* __restrict__ ae3,
                          const float* __restrict__ We4, const float* __restrict__ ae4,
                          float* __restrict__ w_ae_all) {
    int t = threadIdx.x;
    if (t >= 96) return;
    int l = t / 24, idx = t % 24;
    int f = idx >> 3, h = idx & 7;
    const float* We = (l == 0) ? We1 : (l == 1) ? We2 : (l == 2) ? We3 : We4;
    const float* ae = (l == 0) ? ae1 : (l == 1) ? ae2 : (l == 2) ? ae3 : ae4;
    float s = 0.f;
    for (int c = 0; c < Cc; ++c) s += We[f * HC + h * Cc + c] * ae[h * Cc + c];
    w_ae_all[l * 24 + f * 8 + h] = s;
}

__global__ __launch_bounds__(1024) void wsplit_all_k(const float* __restrict__ W2,
                                                     const float* __restrict__ W3,
                                                     const float* __restrict__ W4,
                                                     _Float16* __restrict__ Wt16) {
    __shared__ float tile[32][33];
    int z = blockIdx.z;
    const float* W = (z == 0) ? W2 : (z == 1) ? W3 : W4;
    int nb = blockIdx.x * 32, kb = blockIdx.y * 32;
    tile[threadIdx.y][threadIdx.x] = W[(size_t)(kb + threadIdx.y) * HC + nb + threadIdx.x];
    __syncthreads();
    float x = tile[threadIdx.x][threadIdx.y];   // W[kb+tx][nb+ty]
    int n = nb + threadIdx.y, k = kb + threadIdx.x;
    Wt16[(size_t)z * HC * HC + (size_t)n * HC + k] = (_Float16)x;
}

// ---------------- GEMMs (fused with a_src/a_dst head dots) ----------------

// layer-1 K=5 GEMM + per-head attention dots
__global__ void gemm_k5(const float* __restrict__ x, const float* __restrict__ Wm,
                        const float* __restrict__ a_s, const float* __restrict__ a_d,
                        _Float16* __restrict__ out16,
                        float* __restrict__ a_srcB, float* __restrict__ a_dstB) {
    int n = blockIdx.x;
    int tid = threadIdx.x;
    __shared__ float xr[8];
    __shared__ float vrow[HC];
    if (tid < NF) xr[tid] = x[n * NF + tid];
    __syncthreads();
    float x0 = xr[0], x1 = xr[1], x2 = xr[2], x3 = xr[3], x4 = xr[4];
    for (int j = tid; j < HC; j += 256) {
        float v = x0 * Wm[j] + x1 * Wm[HC + j] + x2 * Wm[2 * HC + j]
                + x3 * Wm[3 * HC + j] + x4 * Wm[4 * HC + j];
        out16[(size_t)n * HC + j] = (_Float16)v;
        vrow[j] = v;
    }
    __syncthreads();
    int w = tid >> 6, lane = tid & 63;
#pragma unroll
    for (int q = 0; q < 2; ++q) {
        int h = w * 2 + q;
        float v0 = vrow[h * Cc + lane], v1 = vrow[h * Cc + 64 + lane];
        float s1 = v0 * a_s[h * Cc + lane] + v1 * a_s[h * Cc + 64 + lane];
        float s2 = v0 * a_d[h * Cc + lane] + v1 * a_d[h * Cc + 64 + lane];
#pragma unroll
        for (int off = 32; off; off >>= 1) {
            s1 += __shfl_xor(s1, off);
            s2 += __shfl_xor(s2, off);
        }
        if (lane == 0) { a_srcB[n * 8 + h] = s1; a_dstB[n * 8 + h] = s2; }
    }
}

// fp16 MFMA GEMM, XCD-aware decode + DOUBLE-BUFFERED 2-phase K-loop (T3-min recipe):
// STAGE(next) issued before compute(current); single vmcnt-drain+barrier per K-step.
// (Round-7: under clean measurement — round-6's rest-time estimate was contaminated
// by the aggregate spill saturating HBM.)
__global__ __launch_bounds__(256) void gemm_mfma(const _Float16* __restrict__ A,
                                                 const _Float16* __restrict__ Bt,
                                                 const float* __restrict__ a_s,
                                                 const float* __restrict__ a_d,
                                                 _Float16* __restrict__ C16,
                                                 float* __restrict__ a_srcB,
                                                 float* __restrict__ a_dstB) {
    __shared__ _Float16 As[2][128 * 32];
    __shared__ _Float16 Bs[2][128 * 32];
    __shared__ float ps[128][2];
    __shared__ float pd[128][2];
    int tid = threadIdx.x;
    int wave = tid >> 6, lane = tid & 63;
    int wr = wave >> 1, wc = wave & 1;
    int L = blockIdx.y * 8 + blockIdx.x;
    int rblk = (L & 7) + 8 * (L >> 6);
    int cblk = (L >> 3) & 7;
    int row0 = rblk * 128;
    int col0 = cblk * 128;
    int h = cblk;   // head

    f32x4 acc[4][4];
#pragma unroll
    for (int i = 0; i < 4; ++i)
#pragma unroll
        for (int j = 0; j < 4; ++j) acc[i][j] = (f32x4){0.f, 0.f, 0.f, 0.f};

    int srow = lane >> 2;          // quad covers 64 contiguous bytes of one row
    int scol = (lane & 3) * 8;
    int fr = lane & 15;
    int fk = (lane >> 4) * 8;

    const _Float16* Ab = A + (size_t)row0 * 1024 + scol;
    const _Float16* Bb = Bt + (size_t)col0 * 1024 + scol;

    // prologue: stage tile 0 into buf 0
#pragma unroll
    for (int cc = 0; cc < 2; ++cc) {
        int c = wave + cc * 4;
        int r = c * 16 + srow;
        gl_lds16(Ab + (size_t)r * 1024, &As[0][c * 512 + lane * 8]);
        gl_lds16(Bb + (size_t)r * 1024, &Bs[0][c * 512 + lane * 8]);
    }
    __syncthreads();   // drains vmcnt (compiler-inserted) — tile 0 resident

    for (int t = 0; t < 32; ++t) {
        int cur = t & 1;
        // issue next-tile stage (lands during MFMA; drained at the barrier below)
        if (t + 1 < 32) {
            int kb = (t + 1) * 32;
#pragma unroll
            for (int cc = 0; cc < 2; ++cc) {
                int c = wave + cc * 4;
                int r = c * 16 + srow;
                gl_lds16(Ab + (size_t)r * 1024 + kb, &As[cur ^ 1][c * 512 + lane * 8]);
                gl_lds16(Bb + (size_t)r * 1024 + kb, &Bs[cur ^ 1][c * 512 + lane * 8]);
            }
        }
        half8 af[4], bf[4];
#pragma unroll
        for (int i = 0; i < 4; ++i)
            af[i] = *(const half8*)&As[cur][(wr * 64 + i * 16 + fr) * 32 + fk];
#pragma unroll
        for (int j = 0; j < 4; ++j)
            bf[j] = *(const half8*)&Bs[cur][(wc * 64 + j * 16 + fr) * 32 + fk];
#pragma unroll
        for (int i = 0; i < 4; ++i)
#pragma unroll
            for (int j = 0; j < 4; ++j)
                acc[i][j] = __builtin_amdgcn_mfma_f32_16x16x32_f16(af[i], bf[j], acc[i][j],
                                                                   0, 0, 0);
        __syncthreads();   // drain vmcnt (next tile landed) + release cur buf
    }

    int cn = lane & 15, rq = (lane >> 4) * 4;
    // C write
#pragma unroll
    for (int i = 0; i < 4; ++i) {
        int rbase = row0 + wr * 64 + i * 16 + rq;
#pragma unroll
        for (int j = 0; j < 4; ++j) {
            int col = col0 + wc * 64 + j * 16 + cn;
#pragma unroll
            for (int r = 0; r < 4; ++r) {
                int row = rbase + r;
                if (row < Nn) C16[(size_t)row * HC + col] = (_Float16)acc[i][j][r];
            }
        }
    }
    // fused a_src/a_dst dots over this head's 128 channels
    float asv[4], adv[4];
#pragma unroll
    for (int j = 0; j < 4; ++j) {
        int c = wc * 64 + j * 16 + cn;
        asv[j] = a_s[h * Cc + c];
        adv[j] = a_d[h * Cc + c];
    }
#pragma unroll
    for (int i = 0; i < 4; ++i)
#pragma unroll
        for (int r = 0; r < 4; ++r) {
            float rs = acc[i][0][r] * asv[0] + acc[i][1][r] * asv[1]
                     + acc[i][2][r] * asv[2] + acc[i][3][r] * asv[3];
            float rd = acc[i][0][r] * adv[0] + acc[i][1][r] * adv[1]
                     + acc[i][2][r] * adv[2] + acc[i][3][r] * adv[3];
#pragma unroll
            for (int off = 1; off < 16; off <<= 1) {
                rs += __shfl_xor(rs, off);
                rd += __shfl_xor(rd, off);
            }
            if (cn == 0) {
                int rib = wr * 64 + i * 16 + rq + r;
                ps[rib][wc] = rs;
                pd[rib][wc] = rd;
            }
        }
    __syncthreads();
    if (tid < 128) {
        int row = row0 + tid;
        if (row < Nn) {
            a_srcB[row * 8 + h] = ps[tid][0] + ps[tid][1];
            a_dstB[row * 8 + h] = pd[tid][0] + pd[tid][1];
        }
    }
}

// ---------------- fused attention aggregate ----------------

// 2 WAVES PER NODE, 2 nodes per 256-block (grid = Nn/2, Nn even).
// EXACT round-2/5 structure (known-good: 57.3 us, VGPR 56, no spills).
// REGISTER-BUDGET CONSTRAINT (r3 + r6 post-mortems): this kernel's working set
// needs >= 56 VGPR. __launch_bounds__(256,8) forced VGPR=32 -> ~1 GB scratch
// traffic, 230 us/layer. (256,4) is the feasible occupancy point; do not raise.
// Coalesced metadata (srcIdx+eaP per 64 edges) + readlane distribution, 4-edge
// unroll (8-edge spilled: r3). Cross-wave combine via conflict-free LDS, 1 barrier.
// mode 0: out = elu(agg+bias) -> fp16 into A2; mode 1: head-mean+bias+elu dot lin_w.
__global__ __launch_bounds__(256, 4) void aggregate_k(const _Float16* __restrict__ xl16,
                                                      const float4* __restrict__ eaP,
                                                      const int* __restrict__ srcIdx,
                                                      const float* __restrict__ loop_attr,
                                                      const float* __restrict__ a_srcB,
                                                      const float* __restrict__ a_dstB,
                                                      const float* __restrict__ w_ae,
                                                      const int* __restrict__ rowptr,
                                                      const float* __restrict__ bias,
                                                      const float* __restrict__ lin_w,
                                                      _Float16* __restrict__ A2,
                                                      float* __restrict__ dnode,
                                                      int raw_mode) {
    __shared__ float cmbA[2][4][256];   // [node][j4][lane*4] — lane-contiguous float4
    __shared__ float cmbS[2][64];
    int tid = threadIdx.x;
    int lane = tid & 63;
    int wav = tid >> 6;
    int local = wav >> 1;                // node within block (0/1)
    int sub = __builtin_amdgcn_readfirstlane(wav & 1);  // edge-half (uniform)
    int n = __builtin_amdgcn_readfirstlane(blockIdx.x * 2 + local);
    int beg = __builtin_amdgcn_readfirstlane(rowptr[n]);
    int end = __builtin_amdgcn_readfirstlane(rowptr[n + 1]);
    int deg = end - beg;
    int hc = lane >> 3;                  // this lane's head

    float w0c = w_ae[hc], w1c = w_ae[8 + hc], w2c = w_ae[16 + hc];
    float adst_n = a_dstB[n * 8 + hc];
    float asrc_n = a_srcB[n * 8 + hc];
    float invd = 1.0f / fmaxf((float)deg, 1.0f);
    float f0 = loop_attr[n * 3 + 0] * invd;
    float f1 = loop_attr[n * 3 + 1] * invd;
    float f2 = loop_attr[n * 3 + 2] * invd;
    float av = asrc_n + adst_n + f0 * w0c + f1 * w1c + f2 * w2c;
    float aself = (av > 0.f) ? av : 0.2f * av;   // softmax shift; self weight = 1

    int hw = (deg + 1) >> 1;
    int myBeg = beg + sub * hw;
    int myEnd = sub ? end : beg + hw;

    int loff = lane * 16;
    float acc[16];
    float s;
    if (sub == 0) {
        // self term (weight exp(0) = 1)
        const _Float16* rp = xl16 + (size_t)n * HC + loff;
        half8 r0 = *(const half8*)rp;
        half8 r1 = *(const half8*)(rp + 8);
#pragma unroll
        for (int j = 0; j < 8; ++j) {
            acc[j] = (float)r0[j];
            acc[8 + j] = (float)r1[j];
        }
        s = 1.0f;
    } else {
#pragma unroll
        for (int j = 0; j < 16; ++j) acc[j] = 0.f;
        s = 0.0f;
    }

    for (int base = myBeg; base < myEnd; base += 64) {
        int cnt = myEnd - base;
        if (cnt > 64) cnt = 64;
        int li = base + ((lane < cnt) ? lane : 0);
        int src_l = srcIdx[li];          // coalesced
        float4 e_l = eaP[li];            // coalesced
        for (int k = 0; k < cnt; k += 4) {
            int k1 = (k + 1 < cnt) ? k + 1 : k;
            int k2 = (k + 2 < cnt) ? k + 2 : k;
            int k3 = (k + 3 < cnt) ? k + 3 : k;
            bool v1 = (k + 1 < cnt), v2 = (k + 2 < cnt), v3 = (k + 3 < cnt);
            int s0 = __builtin_amdgcn_readlane(src_l, k);
            int s1 = __builtin_amdgcn_readlane(src_l, k1);
            int s2 = __builtin_amdgcn_readlane(src_l, k2);
            int s3 = __builtin_amdgcn_readlane(src_l, k3);
            float e0x = rl_f(e_l.x, k),  e0y = rl_f(e_l.y, k),  e0z = rl_f(e_l.z, k);
            float e1x = rl_f(e_l.x, k1), e1y = rl_f(e_l.y, k1), e1z = rl_f(e_l.z, k1);
            float e2x = rl_f(e_l.x, k2), e2y = rl_f(e_l.y, k2), e2z = rl_f(e_l.z, k2);
            float e3x = rl_f(e_l.x, k3), e3y = rl_f(e_l.y, k3), e3z = rl_f(e_l.z, k3);
            float as0 = a_srcB[s0 * 8 + hc], as1 = a_srcB[s1 * 8 + hc];
            float as2 = a_srcB[s2 * 8 + hc], as3 = a_srcB[s3 * 8 + hc];
            const _Float16* p0 = xl16 + (size_t)s0 * HC + loff;
            const _Float16* p1 = xl16 + (size_t)s1 * HC + loff;
            const _Float16* p2 = xl16 + (size_t)s2 * HC + loff;
            const _Float16* p3 = xl16 + (size_t)s3 * HC + loff;
            half8 q0a = *(const half8*)p0, q0b = *(const half8*)(p0 + 8);
            half8 q1a = *(const half8*)p1, q1b = *(const half8*)(p1 + 8);
            half8 q2a = *(const half8*)p2, q2b = *(const half8*)(p2 + 8);
            half8 q3a = *(const half8*)p3, q3b = *(const half8*)(p3 + 8);
            float al0 = as0 + adst_n + e0x * w0c + e0y * w1c + e0z * w2c;
            float al1 = as1 + adst_n + e1x * w0c + e1y * w1c + e1z * w2c;
            float al2 = as2 + adst_n + e2x * w0c + e2y * w1c + e2z * w2c;
            float al3 = as3 + adst_n + e3x * w0c + e3y * w1c + e3z * w2c;
            al0 = (al0 > 0.f) ? al0 : 0.2f * al0;
            al1 = (al1 > 0.f) ? al1 : 0.2f * al1;
            al2 = (al2 > 0.f) ? al2 : 0.2f * al2;
            al3 = (al3 > 0.f) ? al3 : 0.2f * al3;
            float u0 = __expf(al0 - aself);
            float u1 = v1 ? __expf(al1 - aself) : 0.f;
            float u2 = v2 ? __expf(al2 - aself) : 0.f;
            float u3 = v3 ? __expf(al3 - aself) : 0.f;
            s += u0 + u1 + u2 + u3;
#pragma unroll
            for (int j = 0; j < 8; ++j) {
                float t0 = acc[j], t1 = acc[8 + j];
                t0 = fmaf(u0, (float)q0a[j], t0);  t1 = fmaf(u0, (float)q0b[j], t1);
                t0 = fmaf(u1, (float)q1a[j], t0);  t1 = fmaf(u1, (float)q1b[j], t1);
                t0 = fmaf(u2, (float)q2a[j], t0);  t1 = fmaf(u2, (float)q2b[j], t1);
                t0 = fmaf(u3, (float)q3a[j], t0);  t1 = fmaf(u3, (float)q3b[j], t1);
                acc[j] = t0; acc[8 + j] = t1;
            }
        }
    }

    // cross-wave combine (conflict-free: per-lane-contiguous float4, stride 16B)
    if (sub == 1) {
#pragma unroll
        for (int j4 = 0; j4 < 4; ++j4)
            *(float4*)&cmbA[local][j4][lane * 4] =
                make_float4(acc[j4 * 4 + 0], acc[j4 * 4 + 1],
                            acc[j4 * 4 + 2], acc[j4 * 4 + 3]);
        cmbS[local][lane] = s;
    }
    __syncthreads();
    if (sub == 1) return;

    s += cmbS[local][lane];
#pragma unroll
    for (int j4 = 0; j4 < 4; ++j4) {
        float4 c4 = *(const float4*)&cmbA[local][j4][lane * 4];
        acc[j4 * 4 + 0] += c4.x;
        acc[j4 * 4 + 1] += c4.y;
        acc[j4 * 4 + 2] += c4.z;
        acc[j4 * 4 + 3] += c4.w;
    }
    float inv = 1.f / (s + 1e-16f);

    if (!raw_mode) {
        int ch = loff;
        half8 hv0, hv1;
#pragma unroll
        for (int j = 0; j < 8; ++j) {
            hv0[j] = (_Float16)elu_f(fmaf(acc[j], inv, bias[ch + j]));
            hv1[j] = (_Float16)elu_f(fmaf(acc[8 + j], inv, bias[ch + 8 + j]));
        }
        _Float16* p = A2 + (size_t)n * 1024 + ch;
        *(half8*)p = hv0;
        *(half8*)(p + 8) = hv1;
    } else {
        // normalize, then head-mean over the 8 lanes sharing lane&7
#pragma unroll
        for (int j = 0; j < 16; ++j) acc[j] *= inv;
#pragma unroll
        for (int off = 8; off < 64; off <<= 1)
#pragma unroll
            for (int j = 0; j < 16; ++j) acc[j] += __shfl_xor(acc[j], off);
        int c0 = (lane & 7) * 16;
        float partial = 0.f;
#pragma unroll
        for (int j = 0; j < 16; ++j) {
            float v = elu_f(acc[j] * 0.125f + bias[c0 + j]);
            partial = fmaf(v, lin_w[c0 + j], partial);
        }
#pragma unroll
        for (int off = 1; off < 8; off <<= 1) partial += __shfl_xor(partial, off);
        if (lane == 0) dnode[n] = partial;
    }
}

// ---------------- pooling: reduce per-node scalars per group ----------------

__global__ __launch_bounds__(256) void pool_final_k(const float* __restrict__ dnode,
                                                    const int* __restrict__ gstart,
                                                    const float* __restrict__ lin_b,
                                                    float* __restrict__ out) {
    __shared__ float sh[256];
    int g = blockIdx.x;
    int tid = threadIdx.x;
    int s = gstart[g], e = gstart[g + 1];
    float acc = 0.f;
    for (int n = s + tid; n < e; n += 256) acc += dnode[n];
    sh[tid] = acc;
    __syncthreads();
    for (int off = 128; off; off >>= 1) {
        if (tid < off) sh[tid] += sh[tid + off];
        __syncthreads();
    }
    if (tid == 0) out[g] = sh[0] / fmaxf((float)(e - s), 1.f) + lin_b[0];
}

// ---------------- launch ----------------

extern "C" void kernel_launch(void* const* d_in, const int* in_sizes, int n_in,
                              void* d_out, int out_size, void* d_ws, size_t ws_size,
                              hipStream_t stream) {
    const float* x = (const float*)d_in[0];
    const int* ei = (const int*)d_in[1];
    const float* ea = (const float*)d_in[2];
    const int* batch = (const int*)d_in[3];
    const float *Wl[4], *Wel[4], *asl[4], *adl[4], *ael[4], *bl[4];
    for (int l = 0; l < 4; ++l) {
        Wl[l] = (const float*)d_in[4 + 6 * l];
        Wel[l] = (const float*)d_in[5 + 6 * l];
        asl[l] = (const float*)d_in[6 + 6 * l];
        adl[l] = (const float*)d_in[7 + 6 * l];
        ael[l] = (const float*)d_in[8 + 6 * l];
        bl[l] = (const float*)d_in[9 + 6 * l];
    }
    const float* lin_w = (const float*)d_in[28];
    const float* lin_b = (const float*)d_in[29];
    const int* srcA = ei;
    const int* dstA = ei + En;

    float* Wp = (float*)d_ws;
    size_t o = 0;
    _Float16* A2 = (_Float16*)(Wp + o); o += (size_t)MROWS * 512;        // elu acts fp16
    _Float16* Wt16 = (_Float16*)(Wp + o); o += (size_t)3 * HC * HC / 2;  // 3 fp16 W^T
    _Float16* xl16 = (_Float16*)(Wp + o); o += (size_t)Nn * HC / 2;      // xl fp16
    float4* eaP = (float4*)(Wp + o); o += (size_t)En * 4;                // packed ea
    int* srcIdx = (int*)(Wp + o); o += En;                               // CSR src list
    float* loop_attr = Wp + o; o += Nn * 3;                              // RAW ea sums
    int* cnt = (int*)(Wp + o); o += Nn;
    int* rowptr = (int*)(Wp + o); o += Nn + 1;
    int* fillptr = (int*)(Wp + o); o += Nn;
    int* gstart = (int*)(Wp + o); o += Gg + 1;
    float* a_srcB = Wp + o; o += Nn * Hh;
    float* a_dstB = Wp + o; o += Nn * Hh;
    float* w_ae_all = Wp + o; o += 128;
    float* dnode = Wp + o; o += Nn;

    hipMemsetAsync(cnt, 0, Nn * sizeof(int), stream);
    hipMemsetAsync(loop_attr, 0, Nn * 3 * sizeof(float), stream);

    deg_sum_k<<<(En + 255) / 256, 256, 0, stream>>>(dstA, cnt);
    scan_k<<<1, 1024, 0, stream>>>(cnt, rowptr, fillptr, batch, gstart);
    csr_fill_k<<<(En + 255) / 256, 256, 0, stream>>>(srcA, dstA, ea, fillptr, eaP,
                                                     srcIdx, loop_attr);
    wae_all_k<<<1, 128, 0, stream>>>(Wel[0], ael[0], Wel[1], ael[1], Wel[2], ael[2],
                                     Wel[3], ael[3], w_ae_all);
    wsplit_all_k<<<dim3(32, 32, 3), dim3(32, 32), 0, stream>>>(Wl[1], Wl[2], Wl[3], Wt16);

    for (int l = 0; l < 4; ++l) {
        if (l == 0)
            gemm_k5<<<Nn, 256, 0, stream>>>(x, Wl[0], asl[0], adl[0], xl16, a_srcB, a_dstB);
        else
            gemm_mfma<<<dim3(8, MROWS / 128 / 8 * 8), 256, 0, stream>>>(
                A2, Wt16 + (size_t)(l - 1) * HC * HC, asl[l], adl[l], xl16, a_srcB, a_dstB);
        aggregate_k<<<Nn / 2, 256, 0, stream>>>(xl16, eaP, srcIdx, loop_attr, a_srcB,
                                                a_dstB, w_ae_all + l * 24, rowptr,
                                                bl[l], lin_w, A2, dnode,
                                                (l == 3) ? 1 : 0);
    }
    pool_final_k<<<Gg, 256, 0, stream>>>(dnode, gstart, lin_b, (float*)d_out);
}

// Round 8
// 524.598 us; speedup vs baseline: 2.3539x; 1.0513x over previous
//
#include <hip/hip_runtime.h>
#include <math.h>

#define Nn 10000
#define En 160000
#define NF 5
#define EF 3
#define Hh 8
#define Cc 128
#define HC 1024
#define Gg 16

#define MROWS 10240   // 80 * 128 (A rows covered by GEMM grid; >= Nn, pad masked)

typedef __attribute__((ext_vector_type(8))) _Float16 half8;
typedef __attribute__((ext_vector_type(4))) float f32x4;

// ---------------- helpers ----------------

__device__ __forceinline__ void gl_lds16(const void* g, void* l) {
    __builtin_amdgcn_global_load_lds((const __attribute__((address_space(1))) void*)g,
                                     (__attribute__((address_space(3))) void*)l, 16, 0, 0);
}

__device__ __forceinline__ float elu_f(float v) {
    return (v > 0.f) ? v : expm1f(v);
}

__device__ __forceinline__ float rl_f(float v, int k) {
    return __int_as_float(__builtin_amdgcn_readlane(__float_as_int(v), k));
}

// ---------------- preprocessing ----------------

// count-only (1 atomic/edge; the 3 ea-sum atomics moved into csr_fill_k)
__global__ void deg_sum_k(const int* __restrict__ dst, int* __restrict__ cnt) {
    int e = blockIdx.x * 256 + threadIdx.x;
    if (e >= En) return;
    atomicAdd(&cnt[dst[e]], 1);
}

// scan (10 elems/thread + one block scan) + group bounds, fused (no division pass —
// aggregate derives 1/deg from rowptr deltas)
__global__ __launch_bounds__(1024) void scan_k(const int* __restrict__ cnt,
                                               int* __restrict__ rowptr,
                                               int* __restrict__ fillptr,
                                               const int* __restrict__ batch,
                                               int* __restrict__ gstart) {
    __shared__ int sh[1024];
    int tid = threadIdx.x;
    int base = tid * 10;
    int loc[10];
    int tsum = 0;
#pragma unroll
    for (int j = 0; j < 10; ++j) {
        int i = base + j;
        int v = (i < Nn) ? cnt[i] : 0;
        loc[j] = tsum;
        tsum += v;
    }
    sh[tid] = tsum;
    __syncthreads();
    for (int off = 1; off < 1024; off <<= 1) {
        int t = (tid >= off) ? sh[tid - off] : 0;
        __syncthreads();
        sh[tid] += t;
        __syncthreads();
    }
    int excl = sh[tid] - tsum;
#pragma unroll
    for (int j = 0; j < 10; ++j) {
        int i = base + j;
        if (i < Nn) {
            rowptr[i] = excl + loc[j];
            fillptr[i] = excl + loc[j];
        }
    }
    if (tid == 1023) rowptr[Nn] = sh[1023];
#pragma unroll
    for (int j = 0; j < 10; ++j) {
        int i = base + j;
        if (i < Nn) {
            int b = batch[i];
            if (i == 0) {
                for (int g = 0; g <= b; ++g) gstart[g] = 0;
            } else {
                int pb = batch[i - 1];
                for (int g = pb + 1; g <= b; ++g) gstart[g] = i;
            }
            if (i == Nn - 1) {
                for (int g = b + 1; g <= Gg; ++g) gstart[g] = Nn;
            }
        }
    }
}

// CSR fill: packed record (ea0,ea1,ea2) + separate srcIdx + loop_attr raw-sum atomics
__global__ void csr_fill_k(const int* __restrict__ src, const int* __restrict__ dst,
                           const float* __restrict__ ea, int* __restrict__ fillptr,
                           float4* __restrict__ eaP, int* __restrict__ srcIdxW,
                           float* __restrict__ loop_attr) {
    int e = blockIdx.x * 256 + threadIdx.x;
    if (e >= En) return;
    int d = dst[e];
    float e0 = ea[e * 3 + 0], e1 = ea[e * 3 + 1], e2 = ea[e * 3 + 2];
    int sv = src[e];
    int pos = atomicAdd(&fillptr[d], 1);
    eaP[pos] = make_float4(e0, e1, e2, __int_as_float(sv));
    srcIdxW[pos] = sv;
    atomicAdd(&loop_attr[d * 3 + 0], e0);
    atomicAdd(&loop_attr[d * 3 + 1], e1);
    atomicAdd(&loop_attr[d * 3 + 2], e2);
}

// ---------------- weight prep (once, all layers) ----------------

__global__ void wae_all_k(const float* __restrict__ We1, const float* __restrict__ ae1,
                          const float* __restrict__ We2, const float* __restrict__ ae2,
                          const float* __restrict__ We3, const float* __restrict__ ae3,
                          const float* __restrict__ We4, const float* __restrict__ ae4,
                          float* __restrict__ w_ae_all) {
    int t = threadIdx.x;
    if (t >= 96) return;
    int l = t / 24, idx = t % 24;
    int f = idx >> 3, h = idx & 7;
    const float* We = (l == 0) ? We1 : (l == 1) ? We2 : (l == 2) ? We3 : We4;
    const float* ae = (l == 0) ? ae1 : (l == 1) ? ae2 : (l == 2) ? ae3 : ae4;
    float s = 0.f;
    for (int c = 0; c < Cc; ++c) s += We[f * HC + h * Cc + c] * ae[h * Cc + c];
    w_ae_all[l * 24 + f * 8 + h] = s;
}

__global__ __launch_bounds__(1024) void wsplit_all_k(const float* __restrict__ W2,
                                                     const float* __restrict__ W3,
                                                     const float* __restrict__ W4,
                                                     _Float16* __restrict__ Wt16) {
    __shared__ float tile[32][33];
    int z = blockIdx.z;
    const float* W = (z == 0) ? W2 : (z == 1) ? W3 : W4;
    int nb = blockIdx.x * 32, kb = blockIdx.y * 32;
    tile[threadIdx.y][threadIdx.x] = W[(size_t)(kb + threadIdx.y) * HC + nb + threadIdx.x];
    __syncthreads();
    float x = tile[threadIdx.x][threadIdx.y];   // W[kb+tx][nb+ty]
    int n = nb + threadIdx.y, k = kb + threadIdx.x;
    Wt16[(size_t)z * HC * HC + (size_t)n * HC + k] = (_Float16)x;
}

// ---------------- GEMMs (fused with a_src/a_dst head dots) ----------------

// layer-1 K=5 GEMM + per-head attention dots
__global__ void gemm_k5(const float* __restrict__ x, const float* __restrict__ Wm,
                        const float* __restrict__ a_s, const float* __restrict__ a_d,
                        _Float16* __restrict__ out16,
                        float* __restrict__ a_srcB, float* __restrict__ a_dstB) {
    int n = blockIdx.x;
    int tid = threadIdx.x;
    __shared__ float xr[8];
    __shared__ float vrow[HC];
    if (tid < NF) xr[tid] = x[n * NF + tid];
    __syncthreads();
    float x0 = xr[0], x1 = xr[1], x2 = xr[2], x3 = xr[3], x4 = xr[4];
    for (int j = tid; j < HC; j += 256) {
        float v = x0 * Wm[j] + x1 * Wm[HC + j] + x2 * Wm[2 * HC + j]
                + x3 * Wm[3 * HC + j] + x4 * Wm[4 * HC + j];
        out16[(size_t)n * HC + j] = (_Float16)v;
        vrow[j] = v;
    }
    __syncthreads();
    int w = tid >> 6, lane = tid & 63;
#pragma unroll
    for (int q = 0; q < 2; ++q) {
        int h = w * 2 + q;
        float v0 = vrow[h * Cc + lane], v1 = vrow[h * Cc + 64 + lane];
        float s1 = v0 * a_s[h * Cc + lane] + v1 * a_s[h * Cc + 64 + lane];
        float s2 = v0 * a_d[h * Cc + lane] + v1 * a_d[h * Cc + 64 + lane];
#pragma unroll
        for (int off = 32; off; off >>= 1) {
            s1 += __shfl_xor(s1, off);
            s2 += __shfl_xor(s2, off);
        }
        if (lane == 0) { a_srcB[n * 8 + h] = s1; a_dstB[n * 8 + h] = s2; }
    }
}

// fp16 MFMA GEMM (r7 / m97 structure: quad-contiguous staging, [row][32] LDS,
// SINGLE-buffered — r7 post-mortem: explicit dbuf cost 2x LDS -> halved blocks/CU,
// net -15us; implicit wave-overlap already pipelines at this tile size)
// + fused per-head a_src/a_dst dots.
// XCD-aware decode: L = y*8+x; r = (L&7)+8*(L>>6); c = (L>>3)&7. All 8 col-blocks
// of one A row-panel share L mod 8 (same XCD) and are adjacent in dispatch order ->
// the 256 KB A panel is read ONCE per XCD L2 instead of 8x from HBM/L3.
__global__ __launch_bounds__(256) void gemm_mfma(const _Float16* __restrict__ A,
                                                 const _Float16* __restrict__ Bt,
                                                 const float* __restrict__ a_s,
                                                 const float* __restrict__ a_d,
                                                 _Float16* __restrict__ C16,
                                                 float* __restrict__ a_srcB,
                                                 float* __restrict__ a_dstB) {
    __shared__ _Float16 As[128 * 32];
    __shared__ _Float16 Bs[128 * 32];
    __shared__ float ps[128][2];
    __shared__ float pd[128][2];
    int tid = threadIdx.x;
    int wave = tid >> 6, lane = tid & 63;
    int wr = wave >> 1, wc = wave & 1;
    int L = blockIdx.y * 8 + blockIdx.x;
    int rblk = (L & 7) + 8 * (L >> 6);
    int cblk = (L >> 3) & 7;
    int row0 = rblk * 128;
    int col0 = cblk * 128;
    int h = cblk;   // head

    f32x4 acc[4][4];
#pragma unroll
    for (int i = 0; i < 4; ++i)
#pragma unroll
        for (int j = 0; j < 4; ++j) acc[i][j] = (f32x4){0.f, 0.f, 0.f, 0.f};

    int srow = lane >> 2;          // quad covers 64 contiguous bytes of one row
    int scol = (lane & 3) * 8;
    int fr = lane & 15;
    int fk = (lane >> 4) * 8;

    for (int kb = 0; kb < 1024; kb += 32) {
#pragma unroll
        for (int cc = 0; cc < 2; ++cc) {
            int c = wave + cc * 4;
            int r = c * 16 + srow;
            gl_lds16(A + (size_t)(row0 + r) * 1024 + kb + scol, &As[c * 512 + lane * 8]);
            gl_lds16(Bt + (size_t)(col0 + r) * 1024 + kb + scol, &Bs[c * 512 + lane * 8]);
        }
        __syncthreads();

        half8 af[4], bf[4];
#pragma unroll
        for (int i = 0; i < 4; ++i)
            af[i] = *(const half8*)&As[(wr * 64 + i * 16 + fr) * 32 + fk];
#pragma unroll
        for (int j = 0; j < 4; ++j)
            bf[j] = *(const half8*)&Bs[(wc * 64 + j * 16 + fr) * 32 + fk];
#pragma unroll
        for (int i = 0; i < 4; ++i)
#pragma unroll
            for (int j = 0; j < 4; ++j)
                acc[i][j] = __builtin_amdgcn_mfma_f32_16x16x32_f16(af[i], bf[j], acc[i][j],
                                                                   0, 0, 0);
        __syncthreads();
    }

    int cn = lane & 15, rq = (lane >> 4) * 4;
    // C write
#pragma unroll
    for (int i = 0; i < 4; ++i) {
        int rbase = row0 + wr * 64 + i * 16 + rq;
#pragma unroll
        for (int j = 0; j < 4; ++j) {
            int col = col0 + wc * 64 + j * 16 + cn;
#pragma unroll
            for (int r = 0; r < 4; ++r) {
                int row = rbase + r;
                if (row < Nn) C16[(size_t)row * HC + col] = (_Float16)acc[i][j][r];
            }
        }
    }
    // fused a_src/a_dst dots over this head's 128 channels
    float asv[4], adv[4];
#pragma unroll
    for (int j = 0; j < 4; ++j) {
        int c = wc * 64 + j * 16 + cn;
        asv[j] = a_s[h * Cc + c];
        adv[j] = a_d[h * Cc + c];
    }
#pragma unroll
    for (int i = 0; i < 4; ++i)
#pragma unroll
        for (int r = 0; r < 4; ++r) {
            float rs = acc[i][0][r] * asv[0] + acc[i][1][r] * asv[1]
                     + acc[i][2][r] * asv[2] + acc[i][3][r] * asv[3];
            float rd = acc[i][0][r] * adv[0] + acc[i][1][r] * adv[1]
                     + acc[i][2][r] * adv[2] + acc[i][3][r] * adv[3];
#pragma unroll
            for (int off = 1; off < 16; off <<= 1) {
                rs += __shfl_xor(rs, off);
                rd += __shfl_xor(rd, off);
            }
            if (cn == 0) {
                int rib = wr * 64 + i * 16 + rq + r;
                ps[rib][wc] = rs;
                pd[rib][wc] = rd;
            }
        }
    __syncthreads();
    if (tid < 128) {
        int row = row0 + tid;
        if (row < Nn) {
            a_srcB[row * 8 + h] = ps[tid][0] + ps[tid][1];
            a_dstB[row * 8 + h] = pd[tid][0] + pd[tid][1];
        }
    }
}

// ---------------- fused attention aggregate ----------------

// ONE NODE PER 128-THREAD BLOCK (2 waves), grid = Nn. Same inner loop as the
// known-good round-2/5 structure (57.3 us at 2 nodes/256-block); finer block
// granularity: per-node retire (no pairing with a slower sibling node), smaller
// cmb LDS (4.3 KB), better pack/drain for the 10000-block grid.
// REGISTER-BUDGET CONSTRAINT (r3+r6): working set needs >= 56 VGPR; (128,4)
// caps at 128 VGPR — no pressure. Do not tighten.
// Coalesced metadata (srcIdx+eaP per 64 edges) + readlane distribution, 4-edge
// unroll (8-edge spilled: r3). Cross-wave combine via conflict-free LDS, 1 barrier.
// mode 0: out = elu(agg+bias) -> fp16 into A2; mode 1: head-mean+bias+elu dot lin_w.
__global__ __launch_bounds__(128, 4) void aggregate_k(const _Float16* __restrict__ xl16,
                                                      const float4* __restrict__ eaP,
                                                      const int* __restrict__ srcIdx,
                                                      const float* __restrict__ loop_attr,
                                                      const float* __restrict__ a_srcB,
                                                      const float* __restrict__ a_dstB,
                                                      const float* __restrict__ w_ae,
                                                      const int* __restrict__ rowptr,
                                                      const float* __restrict__ bias,
                                                      const float* __restrict__ lin_w,
                                                      _Float16* __restrict__ A2,
                                                      float* __restrict__ dnode,
                                                      int raw_mode) {
    __shared__ float cmbA[4][256];   // [j4][lane*4] — lane-contiguous float4
    __shared__ float cmbS[64];
    int tid = threadIdx.x;
    int lane = tid & 63;
    int sub = __builtin_amdgcn_readfirstlane(tid >> 6);  // edge-half (uniform)
    int n = __builtin_amdgcn_readfirstlane((int)blockIdx.x);
    int beg = __builtin_amdgcn_readfirstlane(rowptr[n]);
    int end = __builtin_amdgcn_readfirstlane(rowptr[n + 1]);
    int deg = end - beg;
    int hc = lane >> 3;                  // this lane's head

    float w0c = w_ae[hc], w1c = w_ae[8 + hc], w2c = w_ae[16 + hc];
    float adst_n = a_dstB[n * 8 + hc];
    float asrc_n = a_srcB[n * 8 + hc];
    float invd = 1.0f / fmaxf((float)deg, 1.0f);
    float f0 = loop_attr[n * 3 + 0] * invd;
    float f1 = loop_attr[n * 3 + 1] * invd;
    float f2 = loop_attr[n * 3 + 2] * invd;
    float av = asrc_n + adst_n + f0 * w0c + f1 * w1c + f2 * w2c;
    float aself = (av > 0.f) ? av : 0.2f * av;   // softmax shift; self weight = 1

    int hw = (deg + 1) >> 1;
    int myBeg = beg + sub * hw;
    int myEnd = sub ? end : beg + hw;

    int loff = lane * 16;
    float acc[16];
    float s;
    if (sub == 0) {
        // self term (weight exp(0) = 1)
        const _Float16* rp = xl16 + (size_t)n * HC + loff;
        half8 r0 = *(const half8*)rp;
        half8 r1 = *(const half8*)(rp + 8);
#pragma unroll
        for (int j = 0; j < 8; ++j) {
            acc[j] = (float)r0[j];
            acc[8 + j] = (float)r1[j];
        }
        s = 1.0f;
    } else {
#pragma unroll
        for (int j = 0; j < 16; ++j) acc[j] = 0.f;
        s = 0.0f;
    }

    for (int base = myBeg; base < myEnd; base += 64) {
        int cnt = myEnd - base;
        if (cnt > 64) cnt = 64;
        int li = base + ((lane < cnt) ? lane : 0);
        int src_l = srcIdx[li];          // coalesced
        float4 e_l = eaP[li];            // coalesced
        for (int k = 0; k < cnt; k += 4) {
            int k1 = (k + 1 < cnt) ? k + 1 : k;
            int k2 = (k + 2 < cnt) ? k + 2 : k;
            int k3 = (k + 3 < cnt) ? k + 3 : k;
            bool v1 = (k + 1 < cnt), v2 = (k + 2 < cnt), v3 = (k + 3 < cnt);
            int s0 = __builtin_amdgcn_readlane(src_l, k);
            int s1 = __builtin_amdgcn_readlane(src_l, k1);
            int s2 = __builtin_amdgcn_readlane(src_l, k2);
            int s3 = __builtin_amdgcn_readlane(src_l, k3);
            float e0x = rl_f(e_l.x, k),  e0y = rl_f(e_l.y, k),  e0z = rl_f(e_l.z, k);
            float e1x = rl_f(e_l.x, k1), e1y = rl_f(e_l.y, k1), e1z = rl_f(e_l.z, k1);
            float e2x = rl_f(e_l.x, k2), e2y = rl_f(e_l.y, k2), e2z = rl_f(e_l.z, k2);
            float e3x = rl_f(e_l.x, k3), e3y = rl_f(e_l.y, k3), e3z = rl_f(e_l.z, k3);
            float as0 = a_srcB[s0 * 8 + hc], as1 = a_srcB[s1 * 8 + hc];
            float as2 = a_srcB[s2 * 8 + hc], as3 = a_srcB[s3 * 8 + hc];
            const _Float16* p0 = xl16 + (size_t)s0 * HC + loff;
            const _Float16* p1 = xl16 + (size_t)s1 * HC + loff;
            const _Float16* p2 = xl16 + (size_t)s2 * HC + loff;
            const _Float16* p3 = xl16 + (size_t)s3 * HC + loff;
            half8 q0a = *(const half8*)p0, q0b = *(const half8*)(p0 + 8);
            half8 q1a = *(const half8*)p1, q1b = *(const half8*)(p1 + 8);
            half8 q2a = *(const half8*)p2, q2b = *(const half8*)(p2 + 8);
            half8 q3a = *(const half8*)p3, q3b = *(const half8*)(p3 + 8);
            float al0 = as0 + adst_n + e0x * w0c + e0y * w1c + e0z * w2c;
            float al1 = as1 + adst_n + e1x * w0c + e1y * w1c + e1z * w2c;
            float al2 = as2 + adst_n + e2x * w0c + e2y * w1c + e2z * w2c;
            float al3 = as3 + adst_n + e3x * w0c + e3y * w1c + e3z * w2c;
            al0 = (al0 > 0.f) ? al0 : 0.2f * al0;
            al1 = (al1 > 0.f) ? al1 : 0.2f * al1;
            al2 = (al2 > 0.f) ? al2 : 0.2f * al2;
            al3 = (al3 > 0.f) ? al3 : 0.2f * al3;
            float u0 = __expf(al0 - aself);
            float u1 = v1 ? __expf(al1 - aself) : 0.f;
            float u2 = v2 ? __expf(al2 - aself) : 0.f;
            float u3 = v3 ? __expf(al3 - aself) : 0.f;
            s += u0 + u1 + u2 + u3;
#pragma unroll
            for (int j = 0; j < 8; ++j) {
                float t0 = acc[j], t1 = acc[8 + j];
                t0 = fmaf(u0, (float)q0a[j], t0);  t1 = fmaf(u0, (float)q0b[j], t1);
                t0 = fmaf(u1, (float)q1a[j], t0);  t1 = fmaf(u1, (float)q1b[j], t1);
                t0 = fmaf(u2, (float)q2a[j], t0);  t1 = fmaf(u2, (float)q2b[j], t1);
                t0 = fmaf(u3, (float)q3a[j], t0);  t1 = fmaf(u3, (float)q3b[j], t1);
                acc[j] = t0; acc[8 + j] = t1;
            }
        }
    }

    // cross-wave combine (conflict-free: per-lane-contiguous float4, stride 16B)
    if (sub == 1) {
#pragma unroll
        for (int j4 = 0; j4 < 4; ++j4)
            *(float4*)&cmbA[j4][lane * 4] =
                make_float4(acc[j4 * 4 + 0], acc[j4 * 4 + 1],
                            acc[j4 * 4 + 2], acc[j4 * 4 + 3]);
        cmbS[lane] = s;
    }
    __syncthreads();
    if (sub == 1) return;

    s += cmbS[lane];
#pragma unroll
    for (int j4 = 0; j4 < 4; ++j4) {
        float4 c4 = *(const float4*)&cmbA[j4][lane * 4];
        acc[j4 * 4 + 0] += c4.x;
        acc[j4 * 4 + 1] += c4.y;
        acc[j4 * 4 + 2] += c4.z;
        acc[j4 * 4 + 3] += c4.w;
    }
    float inv = 1.f / (s + 1e-16f);

    if (!raw_mode) {
        int ch = loff;
        half8 hv0, hv1;
#pragma unroll
        for (int j = 0; j < 8; ++j) {
            hv0[j] = (_Float16)elu_f(fmaf(acc[j], inv, bias[ch + j]));
            hv1[j] = (_Float16)elu_f(fmaf(acc[8 + j], inv, bias[ch + 8 + j]));
        }
        _Float16* p = A2 + (size_t)n * 1024 + ch;
        *(half8*)p = hv0;
        *(half8*)(p + 8) = hv1;
    } else {
        // normalize, then head-mean over the 8 lanes sharing lane&7
#pragma unroll
        for (int j = 0; j < 16; ++j) acc[j] *= inv;
#pragma unroll
        for (int off = 8; off < 64; off <<= 1)
#pragma unroll
            for (int j = 0; j < 16; ++j) acc[j] += __shfl_xor(acc[j], off);
        int c0 = (lane & 7) * 16;
        float partial = 0.f;
#pragma unroll
        for (int j = 0; j < 16; ++j) {
            float v = elu_f(acc[j] * 0.125f + bias[c0 + j]);
            partial = fmaf(v, lin_w[c0 + j], partial);
        }
#pragma unroll
        for (int off = 1; off < 8; off <<= 1) partial += __shfl_xor(partial, off);
        if (lane == 0) dnode[n] = partial;
    }
}

// ---------------- pooling: reduce per-node scalars per group ----------------

__global__ __launch_bounds__(256) void pool_final_k(const float* __restrict__ dnode,
                                                    const int* __restrict__ gstart,
                                                    const float* __restrict__ lin_b,
                                                    float* __restrict__ out) {
    __shared__ float sh[256];
    int g = blockIdx.x;
    int tid = threadIdx.x;
    int s = gstart[g], e = gstart[g + 1];
    float acc = 0.f;
    for (int n = s + tid; n < e; n += 256) acc += dnode[n];
    sh[tid] = acc;
    __syncthreads();
    for (int off = 128; off; off >>= 1) {
        if (tid < off) sh[tid] += sh[tid + off];
        __syncthreads();
    }
    if (tid == 0) out[g] = sh[0] / fmaxf((float)(e - s), 1.f) + lin_b[0];
}

// ---------------- launch ----------------

extern "C" void kernel_launch(void* const* d_in, const int* in_sizes, int n_in,
                              void* d_out, int out_size, void* d_ws, size_t ws_size,
                              hipStream_t stream) {
    const float* x = (const float*)d_in[0];
    const int* ei = (const int*)d_in[1];
    const float* ea = (const float*)d_in[2];
    const int* batch = (const int*)d_in[3];
    const float *Wl[4], *Wel[4], *asl[4], *adl[4], *ael[4], *bl[4];
    for (int l = 0; l < 4; ++l) {
        Wl[l] = (const float*)d_in[4 + 6 * l];
        Wel[l] = (const float*)d_in[5 + 6 * l];
        asl[l] = (const float*)d_in[6 + 6 * l];
        adl[l] = (const float*)d_in[7 + 6 * l];
        ael[l] = (const float*)d_in[8 + 6 * l];
        bl[l] = (const float*)d_in[9 + 6 * l];
    }
    const float* lin_w = (const float*)d_in[28];
    const float* lin_b = (const float*)d_in[29];
    const int* srcA = ei;
    const int* dstA = ei + En;

    float* Wp = (float*)d_ws;
    size_t o = 0;
    _Float16* A2 = (_Float16*)(Wp + o); o += (size_t)MROWS * 512;        // elu acts fp16
    _Float16* Wt16 = (_Float16*)(Wp + o); o += (size_t)3 * HC * HC / 2;  // 3 fp16 W^T
    _Float16* xl16 = (_Float16*)(Wp + o); o += (size_t)Nn * HC / 2;      // xl fp16
    float4* eaP = (float4*)(Wp + o); o += (size_t)En * 4;                // packed ea
    int* srcIdx = (int*)(Wp + o); o += En;                               // CSR src list
    float* loop_attr = Wp + o; o += Nn * 3;                              // RAW ea sums
    int* cnt = (int*)(Wp + o); o += Nn;
    int* rowptr = (int*)(Wp + o); o += Nn + 1;
    int* fillptr = (int*)(Wp + o); o += Nn;
    int* gstart = (int*)(Wp + o); o += Gg + 1;
    float* a_srcB = Wp + o; o += Nn * Hh;
    float* a_dstB = Wp + o; o += Nn * Hh;
    float* w_ae_all = Wp + o; o += 128;
    float* dnode = Wp + o; o += Nn;

    hipMemsetAsync(cnt, 0, Nn * sizeof(int), stream);
    hipMemsetAsync(loop_attr, 0, Nn * 3 * sizeof(float), stream);

    deg_sum_k<<<(En + 255) / 256, 256, 0, stream>>>(dstA, cnt);
    scan_k<<<1, 1024, 0, stream>>>(cnt, rowptr, fillptr, batch, gstart);
    csr_fill_k<<<(En + 255) / 256, 256, 0, stream>>>(srcA, dstA, ea, fillptr, eaP,
                                                     srcIdx, loop_attr);
    wae_all_k<<<1, 128, 0, stream>>>(Wel[0], ael[0], Wel[1], ael[1], Wel[2], ael[2],
                                     Wel[3], ael[3], w_ae_all);
    wsplit_all_k<<<dim3(32, 32, 3), dim3(32, 32), 0, stream>>>(Wl[1], Wl[2], Wl[3], Wt16);

    for (int l = 0; l < 4; ++l) {
        if (l == 0)
            gemm_k5<<<Nn, 256, 0, stream>>>(x, Wl[0], asl[0], adl[0], xl16, a_srcB, a_dstB);
        else
            gemm_mfma<<<dim3(8, MROWS / 128 / 8 * 8), 256, 0, stream>>>(
                A2, Wt16 + (size_t)(l - 1) * HC * HC, asl[l], adl[l], xl16, a_srcB, a_dstB);
        aggregate_k<<<Nn, 128, 0, stream>>>(xl16, eaP, srcIdx, loop_attr, a_srcB,
                                            a_dstB, w_ae_all + l * 24, rowptr,
                                            bl[l], lin_w, A2, dnode,
                                            (l == 3) ? 1 : 0);
    }
    pool_final_k<<<Gg, 256, 0, stream>>>(dnode, gstart, lin_b, (float*)d_out);
}